// Round 4
// baseline (17.495 us; speedup 1.0000x reference)
//
#include <hip/hip_runtime.h>
#include <math.h>

#define DT_STEP 0.01f
#define N_FEAT 15
#define T_CMD 10000
#define ROWS_PER_THREAD 8
#define THREADS 256

__device__ __forceinline__ float4 boat_row(const float4 s, const float4* __restrict__ e) {
    float u = s.x, v = s.y, r = s.z, P = s.w;
    float base[N_FEAT];
    base[1] = u; base[2] = v; base[3] = r; base[4] = P;
    base[5] = u * u; base[6] = u * v; base[7] = u * r; base[8] = u * P;
    base[9] = v * v; base[10] = v * r; base[11] = v * P;
    base[12] = r * r; base[13] = r * P;
    base[14] = P * P;
    float4 acc = e[0];   // feature 0 is the constant 1.0
#pragma unroll
    for (int f = 1; f < N_FEAT; ++f) {
        acc.x = fmaf(base[f], e[f].x, acc.x);
        acc.y = fmaf(base[f], e[f].y, acc.y);
        acc.z = fmaf(base[f], e[f].z, acc.z);
        acc.w = fmaf(base[f], e[f].w, acc.w);
    }
    return acc;
}

__global__ void __launch_bounds__(THREADS) boat_fused(
    const float* __restrict__ t,
    const float* __restrict__ cmd,
    const float* __restrict__ coeffs,
    const float4* __restrict__ state,
    float4* __restrict__ out,
    int nrows)
{
    // ---- uniform effective-coefficient fold ----
    int idx = (int)roundf(t[0] / DT_STEP);
    idx = idx < 0 ? 0 : (idx >= T_CMD ? T_CMD - 1 : idx);
    idx = __builtin_amdgcn_readfirstlane(idx);
    float pro = cmd[2 * idx];
    float rud = cmd[2 * idx + 1];
    float4 e[N_FEAT];
#pragma unroll
    for (int f = 0; f < N_FEAT; ++f) {
        float* ef = &e[f].x;
#pragma unroll
        for (int c = 0; c < 4; ++c) {
            const float* row = coeffs + c * 45;
            ef[c] = fmaf(pro, row[f + 15], fmaf(rud, row[f + 30], row[f]));
        }
    }

    // ---- streaming body: 8 rows/thread, all loads hoisted ----
    int b0 = blockIdx.x * (THREADS * ROWS_PER_THREAD) + threadIdx.x;

    if (b0 + (ROWS_PER_THREAD - 1) * THREADS < nrows) {
        float4 s[ROWS_PER_THREAD];
#pragma unroll
        for (int k = 0; k < ROWS_PER_THREAD; ++k)
            s[k] = state[b0 + k * THREADS];
#pragma unroll
        for (int k = 0; k < ROWS_PER_THREAD; ++k)
            out[b0 + k * THREADS] = boat_row(s[k], e);
    } else {
#pragma unroll
        for (int k = 0; k < ROWS_PER_THREAD; ++k) {
            int b = b0 + k * THREADS;
            if (b < nrows) out[b] = boat_row(state[b], e);
        }
    }
}

extern "C" void kernel_launch(void* const* d_in, const int* in_sizes, int n_in,
                              void* d_out, int out_size, void* d_ws, size_t ws_size,
                              hipStream_t stream) {
    const float* t      = (const float*)d_in[0];
    const float* state  = (const float*)d_in[1];
    const float* cmd    = (const float*)d_in[2];
    const float* coeffs = (const float*)d_in[3];
    float* out = (float*)d_out;

    int nrows = in_sizes[1] / 4;
    int blocks = (nrows + THREADS * ROWS_PER_THREAD - 1) / (THREADS * ROWS_PER_THREAD);

    boat_fused<<<blocks, THREADS, 0, stream>>>(
        t, cmd, coeffs, (const float4*)state, (float4*)out, nrows);
}